// Round 9
// baseline (2074.377 us; speedup 1.0000x reference)
//
#include <hip/hip_runtime.h>

typedef float  f32x4  __attribute__((ext_vector_type(4)));
typedef short  bf16x8 __attribute__((ext_vector_type(8)));

#define DEVI static __device__ __forceinline__

namespace {
constexpr int kL   = 512;
constexpr int kN   = 64;
constexpr int kDH  = 512;
constexpr int kDIN = 512;
constexpr int kG   = 2048;            // 4*kDH
constexpr int kT   = 32;              // timesteps per chunk
constexpr int kChunks = kL / kT;      // 16
constexpr int kHS  = kN * kDH;        // 32768 elements per step slice
constexpr int kFP = 16;               // flag padding: 1 flag per 64B line
constexpr size_t kOutSz = (size_t)kL * kN * kDIN;  // 16,777,216 floats
}

// hsx layout (bf16): [t][chunk=c/8][w=n/16][n%16][c%8]
//   OFF(t,n,c) = t*32768 + (c>>3)*512 + ((n>>4)&3)*128 + (n&15)*8 + (c&7)
// => each producer wave's step output (16 rows x 8 cols) is ONE contiguous
//    256 B block: full-line IC writes, fast vmcnt drain (R7 win).
// flags: per-wave-plane, [w][cg], ONE per 64B line (R8 win + R9 variable).
//   Wave w of any block consumes ONLY rows w*16..+15 => only plane-w flags.
//   Publish after own-wave drain (4 contiguous lines); NO barriers in loop.

DEVI unsigned short f2bf(float f) {
  union { float f; unsigned u; } v; v.f = f;
  unsigned r = v.u + 0x7FFFu + ((v.u >> 16) & 1u);   // RNE
  return (unsigned short)(r >> 16);
}
DEVI float sigm(float z) { return 1.f / (1.f + __expf(-z)); }
DEVI float tanh_f(float z) { return 2.f / (1.f + __expf(-2.f * z)) - 1.f; }

// ---------------------------------------------------------------- prep
__global__ void prep_kernel(
    const float* __restrict__ Wf, const float* __restrict__ Wc,
    const float* __restrict__ Wi, const float* __restrict__ Wo,
    const float* __restrict__ bf, const float* __restrict__ bc,
    const float* __restrict__ bi, const float* __restrict__ bo,
    const float* __restrict__ Wout,
    const float* __restrict__ h0, const float* __restrict__ c0,
    unsigned short* __restrict__ WxT, unsigned short* __restrict__ WoT,
    unsigned short* __restrict__ WhB, float* __restrict__ bg,
    unsigned short* __restrict__ hsx, float* __restrict__ cbuf,
    unsigned int* __restrict__ flags)
{
  const int gid = blockIdx.x * blockDim.x + threadIdx.x;
  const int stride = gridDim.x * blockDim.x;
  const float* Wg[4]  = {Wf, Wc, Wi, Wo};
  const float* bgs[4] = {bf, bc, bi, bo};

  for (int i = gid; i < 256 * kFP; i += stride) flags[i] = 0u;

  for (int i = gid; i < kG * 512; i += stride) {
    int k = i >> 11, g = i & 2047;
    WxT[(size_t)g * 512 + k] = f2bf(Wg[g >> 9][(size_t)k * 512 + (g & 511)]);
  }
  for (int i = gid; i < 512 * 512; i += stride) {
    int k = i >> 9, c = i & 511;
    WoT[(size_t)c * 512 + k] = f2bf(Wout[(size_t)k * 512 + c]);
  }
  // WhB: i = k*1024 + gate*512 + hcol  -> coalesced source reads
  for (int i = gid; i < 4 * 512 * 512; i += stride) {
    int hcol = i & 511;
    int gate = (i >> 9) & 3;
    int k    = i >> 11;
    int cg = hcol >> 3, jj = hcol & 7;
    int n  = gate * 8 + jj;
    int kblk = k >> 3, kin = k & 7;
    size_t dst = ((size_t)cg * 32 + n) * 512 + (((kblk ^ (n & 7)) << 3) | kin);
    WhB[dst] = f2bf(Wg[gate][(size_t)(512 + k) * 512 + hcol]);
  }
  for (int i = gid; i < kG; i += stride) bg[i] = bgs[i >> 9][i & 511];
  for (int i = gid; i < kN * kDH; i += stride) {
    int n = i >> 9, c = i & 511;   // h0[n][c]
    hsx[((size_t)(c >> 3)) * 512 + ((n >> 4) * 128) + ((n & 15) * 8) + (c & 7)]
        = f2bf(h0[i]);             // hsx[0] in chunked layout
    cbuf[i] = c0[i];
  }
}

// Shared-memory overlay for the fused kernel's two roles.
struct SMem {
  union {
    unsigned short WT[32 * 512];                                   // rec: 32 KB
    struct { unsigned short Ash[128][40]; unsigned short Bsh[128][40]; } g;  // 20 KB
  };
};

// ---------------------------------------------------------------- gemm_x body
// Zx2[cg][row][n] = x_row . Wx[:,col] + bg[col]; col = gate*512+cg*8+jj, n = gate*8+jj.
DEVI void gemm_x_tile(SMem& sm, const float* __restrict__ X,
                      const unsigned short* __restrict__ WxT,
                      const float* __restrict__ bg,
                      float* __restrict__ Zx2, int row0, int col0, int tid)
{
  const int lane = tid & 63, wave = tid >> 6;
  const int wr = wave >> 1, wc = wave & 1;
  const int m16 = lane & 15, kg = (lane >> 4) * 8;

  f32x4 acc[4][4] = {};

  for (int k0 = 0; k0 < 512; k0 += 32) {
    __syncthreads();
    #pragma unroll
    for (int i = 0; i < 4; ++i) {
      int idx = i * 256 + tid;
      int r = idx >> 3, kq = idx & 7;
      float4 v = *(const float4*)&X[(size_t)(row0 + r) * 512 + k0 + kq * 4];
      unsigned short* dst = &sm.g.Ash[r][kq * 4];
      dst[0] = f2bf(v.x); dst[1] = f2bf(v.y); dst[2] = f2bf(v.z); dst[3] = f2bf(v.w);
    }
    #pragma unroll
    for (int i = 0; i < 2; ++i) {
      int idx = i * 256 + tid;
      int c = idx >> 2, kq = idx & 3;
      *(uint4*)&sm.g.Bsh[c][kq * 8] =
          *(const uint4*)&WxT[(size_t)(col0 + c) * 512 + k0 + kq * 8];
    }
    __syncthreads();
    bf16x8 fa[4], fb[4];
    #pragma unroll
    for (int mi = 0; mi < 4; ++mi) fa[mi] = *(const bf16x8*)&sm.g.Ash[wr*64 + mi*16 + m16][kg];
    #pragma unroll
    for (int ni = 0; ni < 4; ++ni) fb[ni] = *(const bf16x8*)&sm.g.Bsh[wc*64 + ni*16 + m16][kg];
    #pragma unroll
    for (int mi = 0; mi < 4; ++mi)
      #pragma unroll
      for (int ni = 0; ni < 4; ++ni)
        acc[mi][ni] = __builtin_amdgcn_mfma_f32_16x16x32_bf16(fa[mi], fb[ni], acc[mi][ni], 0, 0, 0);
  }
  const int rg = (lane >> 4) * 4;
  #pragma unroll
  for (int ni = 0; ni < 4; ++ni) {
    int col = col0 + wc*64 + ni*16 + m16;
    float bb = bg[col];
    int gate = col >> 9, hcol = col & 511;
    int cg = hcol >> 3, n = gate * 8 + (hcol & 7);
    #pragma unroll
    for (int mi = 0; mi < 4; ++mi)
      #pragma unroll
      for (int r = 0; r < 4; ++r) {
        int row = row0 + wr*64 + mi*16 + rg + r;
        Zx2[((size_t)cg * 2048 + row) * 32 + n] = acc[mi][ni][r] + bb;
      }
  }
}

// ---------------------------------------------------------------- gemm_x (standalone, chunk 0)
__global__ __launch_bounds__(256) void gemm_x_kernel(
    const float* __restrict__ X, const unsigned short* __restrict__ WxT,
    const float* __restrict__ bg, float* __restrict__ Zx2)
{
  __shared__ SMem sm;
  gemm_x_tile(sm, X, WxT, bg, Zx2, blockIdx.x * 128, blockIdx.y * 128, threadIdx.x);
}

// ---------------------------------------------------------------- fused: rec (blk 0..63) + next-chunk gemm_x (blk 64..255)
__global__ __launch_bounds__(256, 1) void lstm_fused_kernel(
    const unsigned short* __restrict__ WhB,  // [64][32][512] bf16 swizzled
    const float* __restrict__ Zxcur,         // [64][2048][32] this chunk
    unsigned short* __restrict__ hsx,        // [513][...] bf16, chunked layout
    float* __restrict__ cbuf,                // [64][512] fp32
    int step0,
    unsigned int* __restrict__ flags,        // [4][64]*kFP per-wave-plane
    float* __restrict__ dout,
    const float* __restrict__ Xnext,         // next chunk x (null on last)
    const unsigned short* __restrict__ WxT,
    const float* __restrict__ bg,
    float* __restrict__ Zxnext)              // next chunk Zx buffer
{
  __shared__ SMem sm;
  const int tid = threadIdx.x;

  if (blockIdx.x >= 64) {
    // ---------------- gemm role: compute Zx for chunk c+1 ----------------
    if (Xnext == nullptr) return;
    for (int tile = (int)blockIdx.x - 64; tile < 256; tile += 192) {
      gemm_x_tile(sm, Xnext, WxT, bg, Zxnext, (tile >> 4) * 128, (tile & 15) * 128, tid);
      __syncthreads();
    }
    return;
  }

  // ---------------- rec role ----------------
  const int cg = blockIdx.x;
  const int j0 = cg * 8;
  const int w   = tid >> 6;           // wave 0..3 -> batch rows w*16..+16
  const int l   = tid & 63;
  const int q   = l & 15;             // n-col within frag
  const int lg  = l >> 4;             // k-group
  const int jj  = q & 7;
  const int i0  = (q < 8) ? 0 : 2;    // acc rows this lane finishes

  // one-time: W slice -> LDS (linear copy; swizzle pre-applied by prep)
  {
    const uint4* wsrc = (const uint4*)(WhB + (size_t)cg * 32 * 512);
    uint4* wdst = (uint4*)sm.WT;
    #pragma unroll
    for (int i = 0; i < 8; ++i) wdst[i * 256 + tid] = wsrc[i * 256 + tid];
  }
  const size_t cidx = (size_t)(w * 16 + lg * 4 + i0) * 512 + j0 + jj;
  float c0r = cbuf[cidx];
  float c1r = cbuf[cidx + 512];
  __syncthreads();   // only barrier in rec role: W-in-LDS visible to all waves

  // Zx for t=0
  float zc0[4], zc1[4];
  {
    const float* zb = Zxcur + ((size_t)cg * 2048 + (w * 16 + lg * 4)) * 32 + q;
    #pragma unroll
    for (int i = 0; i < 4; ++i) { zc0[i] = zb[i * 32]; zc1[i] = zb[i * 32 + 16]; }
  }

  unsigned int* fplane = flags + (size_t)w * 64 * kFP;   // this plane's flags

  for (int t = 0; t < kT; ++t) {
    const int st = step0 + t;

    // wait for this plane's hsx rows at step st (skip t=0: previous dispatch
    // completed it). All lanes poll; lane l watches block l's plane-w flag
    // (64 distinct 64B lines). No barrier: publish below is per-wave too.
    if (t > 0) {
      for (;;) {
        int fv = (int)__hip_atomic_load(&fplane[l * kFP], __ATOMIC_RELAXED,
                                        __HIP_MEMORY_SCOPE_AGENT);
        if (__all(fv >= st)) break;
      }
      asm volatile("" ::: "memory");   // keep A-loads below the gate
    }

    // A-frags from chunked layout: A[s] = row w*16+q, cols 8*(4s+lg)..+7
    const unsigned short* hrow =
        hsx + (size_t)st * kHS + (size_t)lg * 512 + w * 128 + q * 8;
    bf16x8 A[16];
    #pragma unroll
    for (int s = 0; s < 16; ++s) A[s] = *(const bf16x8*)(hrow + 2048 * s);

    // Zx prefetch for t+1 issued BEFORE MFMA: completes under compute, so the
    // vmcnt(0) drain below only pays the h-store round trip.
    float zn0[4], zn1[4];
    if (t + 1 < kT) {
      const float* zb = Zxcur +
          ((size_t)cg * 2048 + ((t + 1) * 64 + w * 16 + lg * 4)) * 32 + q;
      #pragma unroll
      for (int i = 0; i < 4; ++i) { zn0[i] = zb[i * 32]; zn1[i] = zb[i * 32 + 16]; }
    }

    // MFMA: 16 ksteps x 2 n-frags
    f32x4 acc0 = {}, acc1 = {};
    #pragma unroll
    for (int s = 0; s < 16; ++s) {
      const int kb = 4 * s + lg;
      bf16x8 b0 = *(const bf16x8*)&sm.WT[(size_t)q * 512 + ((kb ^ jj) << 3)];
      bf16x8 b1 = *(const bf16x8*)&sm.WT[(size_t)(16 + q) * 512 + ((kb ^ jj) << 3)];
      acc0 = __builtin_amdgcn_mfma_f32_16x16x32_bf16(A[s], b0, acc0, 0, 0, 0);
      acc1 = __builtin_amdgcn_mfma_f32_16x16x32_bf16(A[s], b1, acc1, 0, 0, 0);
    }

    // z = acc + Zx (own cols), then exchange with lane^8 to gather 4 gates
    float t0[4], t1[4], ot0[4], ot1[4];
    #pragma unroll
    for (int i = 0; i < 4; ++i) { t0[i] = acc0[i] + zc0[i]; t1[i] = acc1[i] + zc1[i]; }
    #pragma unroll
    for (int i = 0; i < 4; ++i) {
      ot0[i] = __shfl_xor(t0[i], 8, 64);
      ot1[i] = __shfl_xor(t1[i], 8, 64);
    }
    float hh[2];
    #pragma unroll
    for (int u = 0; u < 2; ++u) {
      const int i = i0 + u;
      float zf = (q < 8) ? t0[i] : ot0[i];
      float zc = (q < 8) ? ot0[i] : t0[i];
      float zi = (q < 8) ? t1[i] : ot1[i];
      float zo = (q < 8) ? ot1[i] : t1[i];
      float fg = sigm(zf), ig = sigm(zi), og = sigm(zo);
      float Ct = tanh_f(zc);
      float& cr = u ? c1r : c0r;
      cr = fg * cr + ig * Ct;
      hh[u] = og * tanh_f(cr);
    }

    // store h: wave's 16x8 tile is ONE contiguous 256 B block (R7)
    {
      unsigned short hb0 = f2bf(hh[0]), hb1 = f2bf(hh[1]);
      unsigned o0 = (unsigned)(unsigned short)__shfl_xor((int)hb0, 1, 64);
      unsigned o1 = (unsigned)(unsigned short)__shfl_xor((int)hb1, 1, 64);
      if ((q & 1) == 0) {
        const size_t base = (size_t)(st + 1) * kHS + (size_t)cg * 512 +
                            w * 128 + (lg * 4 + i0) * 8 + jj;
        __hip_atomic_store((unsigned*)&hsx[base], ((unsigned)hb0) | (o0 << 16),
                           __ATOMIC_RELAXED, __HIP_MEMORY_SCOPE_AGENT);
        __hip_atomic_store((unsigned*)&hsx[base + 8], ((unsigned)hb1) | (o1 << 16),
                           __ATOMIC_RELAXED, __HIP_MEMORY_SCOPE_AGENT);
      }
      if (st == kL - 1) {
        dout[kOutSz + cidx] = hh[0];
        dout[kOutSz + cidx + 512] = hh[1];
        dout[kOutSz + (size_t)kN * kDH + cidx] = c0r;
        dout[kOutSz + (size_t)kN * kDH + cidx + 512] = c1r;
      }
    }

    // drain THIS wave's h stores (4 contiguous lines), then publish this
    // wave's plane flag (own 64B line). No barrier.
    asm volatile("s_waitcnt vmcnt(0)" ::: "memory");
    if (l == 0)
      __hip_atomic_store(&fplane[cg * kFP], (unsigned)(st + 1),
                         __ATOMIC_RELAXED, __HIP_MEMORY_SCOPE_AGENT);

    if (t + 1 < kT) {
      #pragma unroll
      for (int i = 0; i < 4; ++i) { zc0[i] = zn0[i]; zc1[i] = zn1[i]; }
    }
  }

  cbuf[cidx] = c0r;
  cbuf[cidx + 512] = c1r;
}

// ---------------------------------------------------------------- gemm_out
__global__ __launch_bounds__(256) void gemm_out_kernel(
    const unsigned short* __restrict__ Hs,   // hsx + 32768: h_1.. in chunked layout
    const unsigned short* __restrict__ WoT,  // [512][512] bf16 (B^T)
    const float* __restrict__ bout,
    float* __restrict__ out)                 // [32768][512] fp32
{
  __shared__ unsigned short Ash[128][40];
  __shared__ unsigned short Bsh[128][40];
  const int row0 = blockIdx.x * 128, col0 = blockIdx.y * 128;
  const int tid = threadIdx.x;
  const int lane = tid & 63, wave = tid >> 6;
  const int wr = wave >> 1, wc = wave & 1;
  const int m16 = lane & 15, kg = (lane >> 4) * 8;

  f32x4 acc[4][4] = {};

  for (int k0 = 0; k0 < 512; k0 += 32) {
    __syncthreads();
    #pragma unroll
    for (int i = 0; i < 2; ++i) {
      int idx = i * 256 + tid;
      int r = idx >> 2, kq = idx & 3;
      int grow = row0 + r;               // h row: t*64 + n  (t = step-1)
      size_t src = (size_t)(grow >> 6) * kHS + (size_t)((k0 >> 3) + kq) * 512 +
                   ((grow >> 4) & 3) * 128 + (grow & 15) * 8;
      *(uint4*)&Ash[r][kq * 8] = *(const uint4*)&Hs[src];
    }
    #pragma unroll
    for (int i = 0; i < 2; ++i) {
      int idx = i * 256 + tid;
      int c = idx >> 2, kq = idx & 3;
      *(uint4*)&Bsh[c][kq * 8] =
          *(const uint4*)&WoT[(size_t)(col0 + c) * 512 + k0 + kq * 8];
    }
    __syncthreads();
    bf16x8 fa[4], fb[4];
    #pragma unroll
    for (int mi = 0; mi < 4; ++mi) fa[mi] = *(const bf16x8*)&Ash[wr*64 + mi*16 + m16][kg];
    #pragma unroll
    for (int ni = 0; ni < 4; ++ni) fb[ni] = *(const bf16x8*)&Bsh[wc*64 + ni*16 + m16][kg];
    #pragma unroll
    for (int mi = 0; mi < 4; ++mi)
      #pragma unroll
      for (int ni = 0; ni < 4; ++ni)
        acc[mi][ni] = __builtin_amdgcn_mfma_f32_16x16x32_bf16(fa[mi], fb[ni], acc[mi][ni], 0, 0, 0);
  }
  const int rg = (lane >> 4) * 4;
  #pragma unroll
  for (int ni = 0; ni < 4; ++ni) {
    int col = col0 + wc*64 + ni*16 + m16;
    float bb = bout[col];
    #pragma unroll
    for (int mi = 0; mi < 4; ++mi)
      #pragma unroll
      for (int r = 0; r < 4; ++r)
        out[(size_t)(row0 + wr*64 + mi*16 + rg + r) * 512 + col] = acc[mi][ni][r] + bb;
  }
}

// ---------------------------------------------------------------- launch
extern "C" void kernel_launch(void* const* d_in, const int* in_sizes, int n_in,
                              void* d_out, int out_size, void* d_ws, size_t ws_size,
                              hipStream_t stream) {
  (void)in_sizes; (void)n_in; (void)out_size; (void)ws_size;
  const float* x    = (const float*)d_in[0];
  const float* h0   = (const float*)d_in[1];
  const float* c0   = (const float*)d_in[2];
  const float* Wf   = (const float*)d_in[3];
  const float* bf_  = (const float*)d_in[4];
  const float* Wc   = (const float*)d_in[5];
  const float* bc_  = (const float*)d_in[6];
  const float* Wi_  = (const float*)d_in[7];
  const float* bi_  = (const float*)d_in[8];
  const float* Wo   = (const float*)d_in[9];
  const float* bo_  = (const float*)d_in[10];
  const float* Wout = (const float*)d_in[11];
  const float* bout = (const float*)d_in[12];
  float* out = (float*)d_out;

  char* ws = (char*)d_ws;
  size_t off = 0;
  auto alloc = [&](size_t bytes) -> void* {
    void* p = ws + off;
    off += (bytes + 255) & ~(size_t)255;
    return p;
  };
  float*          ZxA = (float*)alloc((size_t)kT * kN * kG * 4);                 // 16 MB
  float*          ZxB = (float*)alloc((size_t)kT * kN * kG * 4);                 // 16 MB
  unsigned short* hsx = (unsigned short*)alloc((size_t)(kL + 1) * kN * kDH * 2); // 33.6 MB
  unsigned short* WxT = (unsigned short*)alloc((size_t)kG * 512 * 2);            // 2 MB
  unsigned short* WoT = (unsigned short*)alloc((size_t)512 * 512 * 2);           // 0.5 MB
  unsigned short* WhB = (unsigned short*)alloc((size_t)64 * 32 * 512 * 2);       // 2 MB
  float*          bg  = (float*)alloc((size_t)kG * 4);
  float*          cbf = (float*)alloc((size_t)kN * kDH * 4);
  unsigned int*   flg = (unsigned int*)alloc((size_t)256 * kFP * 4);             // 16 KB

  prep_kernel<<<1024, 256, 0, stream>>>(Wf, Wc, Wi_, Wo, bf_, bc_, bi_, bo_,
                                        Wout, h0, c0, WxT, WoT, WhB, bg, hsx, cbf, flg);
  // chunk 0's Zx
  gemm_x_kernel<<<dim3(16, 16), 256, 0, stream>>>(x, WxT, bg, ZxA);
  for (int c = 0; c < kChunks; ++c) {
    float* Zxcur = (c & 1) ? ZxB : ZxA;
    float* Zxnxt = (c & 1) ? ZxA : ZxB;
    const float* xnext = (c + 1 < kChunks)
        ? x + (size_t)(c + 1) * kT * kN * kDIN : nullptr;
    lstm_fused_kernel<<<256, 256, 0, stream>>>(
        WhB, Zxcur, hsx, cbf, c * kT, flg, out, xnext, WxT, bg, Zxnxt);
  }
  gemm_out_kernel<<<dim3(256, 4), 256, 0, stream>>>(
      hsx + (size_t)kN * kDH, WoT, bout, out);
}

// Round 10
// 1727.051 us; speedup vs baseline: 1.2011x; 1.2011x over previous
//
#include <hip/hip_runtime.h>

typedef float  f32x4  __attribute__((ext_vector_type(4)));
typedef short  bf16x8 __attribute__((ext_vector_type(8)));

#define DEVI static __device__ __forceinline__

namespace {
constexpr int kL   = 512;
constexpr int kN   = 64;
constexpr int kDH  = 512;
constexpr int kDIN = 512;
constexpr int kG   = 2048;            // 4*kDH
constexpr int kT   = 32;              // timesteps per chunk
constexpr int kChunks = kL / kT;      // 16
constexpr int kHS  = kN * kDH;        // 32768 elements per step slice
constexpr int kFP = 16;               // flag padding: 1 flag per 64B line
constexpr size_t kOutSz = (size_t)kL * kN * kDIN;  // 16,777,216 floats
}

// hsx layout (bf16): [t][chunk=c/8][w=n/16][n%16][c%8]  (R7 win)
// flags: one per 64B line, wave0-poll + barrier + block publish (R8 win)
// Zx layout (R10): [cg][t][lane(256)][8] -> each rec lane's step slice is
//   32B contiguous (2x f32x4); gemm_x epilogue writes this order.
// B-fragments (R10): preloaded to 128 VGPRs once; no in-loop LDS reads.

DEVI unsigned short f2bf(float f) {
  union { float f; unsigned u; } v; v.f = f;
  unsigned r = v.u + 0x7FFFu + ((v.u >> 16) & 1u);   // RNE
  return (unsigned short)(r >> 16);
}
DEVI float sigm(float z) { return 1.f / (1.f + __expf(-z)); }
DEVI float tanh_f(float z) { return 2.f / (1.f + __expf(-2.f * z)) - 1.f; }

// ---------------------------------------------------------------- prep
__global__ void prep_kernel(
    const float* __restrict__ Wf, const float* __restrict__ Wc,
    const float* __restrict__ Wi, const float* __restrict__ Wo,
    const float* __restrict__ bf, const float* __restrict__ bc,
    const float* __restrict__ bi, const float* __restrict__ bo,
    const float* __restrict__ Wout,
    const float* __restrict__ h0, const float* __restrict__ c0,
    unsigned short* __restrict__ WxT, unsigned short* __restrict__ WoT,
    unsigned short* __restrict__ WhB, float* __restrict__ bg,
    unsigned short* __restrict__ hsx, float* __restrict__ cbuf,
    unsigned int* __restrict__ flags)
{
  const int gid = blockIdx.x * blockDim.x + threadIdx.x;
  const int stride = gridDim.x * blockDim.x;
  const float* Wg[4]  = {Wf, Wc, Wi, Wo};
  const float* bgs[4] = {bf, bc, bi, bo};

  for (int i = gid; i < 64 * kFP; i += stride) flags[i] = 0u;

  for (int i = gid; i < kG * 512; i += stride) {
    int k = i >> 11, g = i & 2047;
    WxT[(size_t)g * 512 + k] = f2bf(Wg[g >> 9][(size_t)k * 512 + (g & 511)]);
  }
  for (int i = gid; i < 512 * 512; i += stride) {
    int k = i >> 9, c = i & 511;
    WoT[(size_t)c * 512 + k] = f2bf(Wout[(size_t)k * 512 + c]);
  }
  // WhB: i = k*1024 + gate*512 + hcol  -> coalesced source reads
  for (int i = gid; i < 4 * 512 * 512; i += stride) {
    int hcol = i & 511;
    int gate = (i >> 9) & 3;
    int k    = i >> 11;
    int cg = hcol >> 3, jj = hcol & 7;
    int n  = gate * 8 + jj;
    int kblk = k >> 3, kin = k & 7;
    size_t dst = ((size_t)cg * 32 + n) * 512 + (((kblk ^ (n & 7)) << 3) | kin);
    WhB[dst] = f2bf(Wg[gate][(size_t)(512 + k) * 512 + hcol]);
  }
  for (int i = gid; i < kG; i += stride) bg[i] = bgs[i >> 9][i & 511];
  for (int i = gid; i < kN * kDH; i += stride) {
    int n = i >> 9, c = i & 511;   // h0[n][c]
    hsx[((size_t)(c >> 3)) * 512 + ((n >> 4) * 128) + ((n & 15) * 8) + (c & 7)]
        = f2bf(h0[i]);             // hsx[0] in chunked layout
    cbuf[i] = c0[i];
  }
}

// Shared-memory overlay for the fused kernel's two roles.
struct SMem {
  union {
    unsigned short WT[32 * 512];                                   // rec: 32 KB
    struct { unsigned short Ash[128][40]; unsigned short Bsh[128][40]; } g;  // 20 KB
  };
};

// ---------------------------------------------------------------- gemm_x body
// z[row][col] with col = gate*512 + cg*8 + jj; n = gate*8+jj; q=n&15, half=n>>4.
// Write to lane-swizzled Zx: [(cg*32 + t)*256 + (w*64+lg*16+q)]*8 + i*2 + half,
// where row = t*64 + w*16 + lg*4 + i.
DEVI void gemm_x_tile(SMem& sm, const float* __restrict__ X,
                      const unsigned short* __restrict__ WxT,
                      const float* __restrict__ bg,
                      float* __restrict__ Zx2, int row0, int col0, int tid)
{
  const int lane = tid & 63, wave = tid >> 6;
  const int wr = wave >> 1, wc = wave & 1;
  const int m16 = lane & 15, kg = (lane >> 4) * 8;

  f32x4 acc[4][4] = {};

  for (int k0 = 0; k0 < 512; k0 += 32) {
    __syncthreads();
    #pragma unroll
    for (int i = 0; i < 4; ++i) {
      int idx = i * 256 + tid;
      int r = idx >> 3, kq = idx & 7;
      float4 v = *(const float4*)&X[(size_t)(row0 + r) * 512 + k0 + kq * 4];
      unsigned short* dst = &sm.g.Ash[r][kq * 4];
      dst[0] = f2bf(v.x); dst[1] = f2bf(v.y); dst[2] = f2bf(v.z); dst[3] = f2bf(v.w);
    }
    #pragma unroll
    for (int i = 0; i < 2; ++i) {
      int idx = i * 256 + tid;
      int c = idx >> 2, kq = idx & 3;
      *(uint4*)&sm.g.Bsh[c][kq * 8] =
          *(const uint4*)&WxT[(size_t)(col0 + c) * 512 + k0 + kq * 8];
    }
    __syncthreads();
    bf16x8 fa[4], fb[4];
    #pragma unroll
    for (int mi = 0; mi < 4; ++mi) fa[mi] = *(const bf16x8*)&sm.g.Ash[wr*64 + mi*16 + m16][kg];
    #pragma unroll
    for (int ni = 0; ni < 4; ++ni) fb[ni] = *(const bf16x8*)&sm.g.Bsh[wc*64 + ni*16 + m16][kg];
    #pragma unroll
    for (int mi = 0; mi < 4; ++mi)
      #pragma unroll
      for (int ni = 0; ni < 4; ++ni)
        acc[mi][ni] = __builtin_amdgcn_mfma_f32_16x16x32_bf16(fa[mi], fb[ni], acc[mi][ni], 0, 0, 0);
  }
  const int rg = (lane >> 4) * 4;
  #pragma unroll
  for (int ni = 0; ni < 4; ++ni) {
    int col = col0 + wc*64 + ni*16 + m16;
    float bb = bg[col];
    int gate = col >> 9, hcol = col & 511;
    int cg = hcol >> 3, n = gate * 8 + (hcol & 7);
    int qn = n & 15, half = n >> 4;
    #pragma unroll
    for (int mi = 0; mi < 4; ++mi)
      #pragma unroll
      for (int r = 0; r < 4; ++r) {
        int row = row0 + wr*64 + mi*16 + rg + r;
        int t = row >> 6, b = row & 63;
        int wv = b >> 4, lgv = (b >> 2) & 3, iv = b & 3;
        Zx2[((size_t)(cg * 32 + t) * 256 + (wv * 64 + lgv * 16 + qn)) * 8 +
            iv * 2 + half] = acc[mi][ni][r] + bb;
      }
  }
}

// ---------------------------------------------------------------- gemm_x (standalone, chunk 0)
__global__ __launch_bounds__(256) void gemm_x_kernel(
    const float* __restrict__ X, const unsigned short* __restrict__ WxT,
    const float* __restrict__ bg, float* __restrict__ Zx2)
{
  __shared__ SMem sm;
  gemm_x_tile(sm, X, WxT, bg, Zx2, blockIdx.x * 128, blockIdx.y * 128, threadIdx.x);
}

// ---------------------------------------------------------------- fused: rec (blk 0..63) + next-chunk gemm_x (blk 64..255)
__global__ __launch_bounds__(256, 1) void lstm_fused_kernel(
    const unsigned short* __restrict__ WhB,  // [64][32][512] bf16 swizzled
    const float* __restrict__ Zxcur,         // [64][32][256][8] lane-swizzled
    unsigned short* __restrict__ hsx,        // [513][...] bf16, chunked layout
    float* __restrict__ cbuf,                // [64][512] fp32
    int step0,
    unsigned int* __restrict__ flags,        // [64*kFP], flag at cg*kFP
    float* __restrict__ dout,
    const float* __restrict__ Xnext,         // next chunk x (null on last)
    const unsigned short* __restrict__ WxT,
    const float* __restrict__ bg,
    float* __restrict__ Zxnext)              // next chunk Zx buffer
{
  __shared__ SMem sm;
  const int tid = threadIdx.x;

  if (blockIdx.x >= 64) {
    // ---------------- gemm role: compute Zx for chunk c+1 ----------------
    if (Xnext == nullptr) return;
    for (int tile = (int)blockIdx.x - 64; tile < 256; tile += 192) {
      gemm_x_tile(sm, Xnext, WxT, bg, Zxnext, (tile >> 4) * 128, (tile & 15) * 128, tid);
      __syncthreads();
    }
    return;
  }

  // ---------------- rec role ----------------
  const int cg = blockIdx.x;
  const int j0 = cg * 8;
  const int w   = tid >> 6;           // wave 0..3 -> batch rows w*16..+16
  const int l   = tid & 63;
  const int q   = l & 15;             // n-col within frag
  const int lg  = l >> 4;             // k-group
  const int jj  = q & 7;
  const int i0  = (q < 8) ? 0 : 2;    // acc rows this lane finishes

  // one-time: W slice -> LDS (linear copy; swizzle pre-applied by prep)
  {
    const uint4* wsrc = (const uint4*)(WhB + (size_t)cg * 32 * 512);
    uint4* wdst = (uint4*)sm.WT;
    #pragma unroll
    for (int i = 0; i < 8; ++i) wdst[i * 256 + tid] = wsrc[i * 256 + tid];
  }
  const size_t cidx = (size_t)(w * 16 + lg * 4 + i0) * 512 + j0 + jj;
  float c0r = cbuf[cidx];
  float c1r = cbuf[cidx + 512];
  __syncthreads();

  // one-time: preload ALL B fragments into registers (W is step-invariant).
  // 32 x bf16x8 = 128 VGPR; static indices only (unrolled) to stay in regs.
  bf16x8 B0[16], B1[16];
  #pragma unroll
  for (int s = 0; s < 16; ++s) {
    const int kb = 4 * s + lg;
    B0[s] = *(const bf16x8*)&sm.WT[(size_t)q * 512 + ((kb ^ jj) << 3)];
    B1[s] = *(const bf16x8*)&sm.WT[(size_t)(16 + q) * 512 + ((kb ^ jj) << 3)];
  }

  // Zx base for this lane: 8 floats per step, 2048 floats per step per block
  const float* zbase = Zxcur + (size_t)cg * 32 * 2048 + (size_t)tid * 8;

  // Zx for t=0 (2 x f32x4, 32B contiguous per lane)
  float zc0[4], zc1[4];
  {
    f32x4 a = *(const f32x4*)zbase;
    f32x4 b = *(const f32x4*)(zbase + 4);
    zc0[0] = a[0]; zc1[0] = a[1]; zc0[1] = a[2]; zc1[1] = a[3];
    zc0[2] = b[0]; zc1[2] = b[1]; zc0[3] = b[2]; zc1[3] = b[3];
  }

  for (int t = 0; t < kT; ++t) {
    const int st = step0 + t;

    // wait for hsx[st] (skip t=0: previous dispatch completed it).
    // Wave 0 polls: lane l watches flags[l*kFP] (64 distinct lines).
    if (t > 0) {
      if (tid < 64) {
        for (;;) {
          int fv = (int)__hip_atomic_load(&flags[l * kFP], __ATOMIC_RELAXED,
                                          __HIP_MEMORY_SCOPE_AGENT);
          if (__all(fv >= st)) break;
        }
      }
      __syncthreads();
    }

    // A-frags from chunked layout: A[s] = row w*16+q, cols 8*(4s+lg)..+7
    const unsigned short* hrow =
        hsx + (size_t)st * kHS + (size_t)lg * 512 + w * 128 + q * 8;
    bf16x8 A[16];
    #pragma unroll
    for (int s = 0; s < 16; ++s) A[s] = *(const bf16x8*)(hrow + 2048 * s);

    // Zx prefetch for t+1 issued BEFORE MFMA: completes under compute.
    float zn0[4], zn1[4];
    if (t + 1 < kT) {
      const float* zb = zbase + (size_t)(t + 1) * 2048;
      f32x4 a = *(const f32x4*)zb;
      f32x4 b = *(const f32x4*)(zb + 4);
      zn0[0] = a[0]; zn1[0] = a[1]; zn0[1] = a[2]; zn1[1] = a[3];
      zn0[2] = b[0]; zn1[2] = b[1]; zn0[3] = b[2]; zn1[3] = b[3];
    }

    // MFMA: 16 ksteps x 2 n-frags, B from registers (no LDS in loop)
    f32x4 acc0 = {}, acc1 = {};
    #pragma unroll
    for (int s = 0; s < 16; ++s) {
      acc0 = __builtin_amdgcn_mfma_f32_16x16x32_bf16(A[s], B0[s], acc0, 0, 0, 0);
      acc1 = __builtin_amdgcn_mfma_f32_16x16x32_bf16(A[s], B1[s], acc1, 0, 0, 0);
    }

    // z = acc + Zx (own cols), then exchange with lane^8 to gather 4 gates
    float t0[4], t1[4], ot0[4], ot1[4];
    #pragma unroll
    for (int i = 0; i < 4; ++i) { t0[i] = acc0[i] + zc0[i]; t1[i] = acc1[i] + zc1[i]; }
    #pragma unroll
    for (int i = 0; i < 4; ++i) {
      ot0[i] = __shfl_xor(t0[i], 8, 64);
      ot1[i] = __shfl_xor(t1[i], 8, 64);
    }
    float hh[2];
    #pragma unroll
    for (int u = 0; u < 2; ++u) {
      const int i = i0 + u;
      float zf = (q < 8) ? t0[i] : ot0[i];
      float zc = (q < 8) ? ot0[i] : t0[i];
      float zi = (q < 8) ? t1[i] : ot1[i];
      float zo = (q < 8) ? ot1[i] : t1[i];
      float fg = sigm(zf), ig = sigm(zi), og = sigm(zo);
      float Ct = tanh_f(zc);
      float& cr = u ? c1r : c0r;
      cr = fg * cr + ig * Ct;
      hh[u] = og * tanh_f(cr);
    }

    // store h: wave's 16x8 tile is ONE contiguous 256 B block (R7)
    {
      unsigned short hb0 = f2bf(hh[0]), hb1 = f2bf(hh[1]);
      unsigned o0 = (unsigned)(unsigned short)__shfl_xor((int)hb0, 1, 64);
      unsigned o1 = (unsigned)(unsigned short)__shfl_xor((int)hb1, 1, 64);
      if ((q & 1) == 0) {
        const size_t base = (size_t)(st + 1) * kHS + (size_t)cg * 512 +
                            w * 128 + (lg * 4 + i0) * 8 + jj;
        __hip_atomic_store((unsigned*)&hsx[base], ((unsigned)hb0) | (o0 << 16),
                           __ATOMIC_RELAXED, __HIP_MEMORY_SCOPE_AGENT);
        __hip_atomic_store((unsigned*)&hsx[base + 8], ((unsigned)hb1) | (o1 << 16),
                           __ATOMIC_RELAXED, __HIP_MEMORY_SCOPE_AGENT);
      }
      if (st == kL - 1) {
        dout[kOutSz + cidx] = hh[0];
        dout[kOutSz + cidx + 512] = hh[1];
        dout[kOutSz + (size_t)kN * kDH + cidx] = c0r;
        dout[kOutSz + (size_t)kN * kDH + cidx + 512] = c1r;
      }
    }

    // drain h stores, then publish flag (own 64B line)
    asm volatile("s_waitcnt vmcnt(0)" ::: "memory");
    __syncthreads();
    if (tid == 0)
      __hip_atomic_store(&flags[cg * kFP], (unsigned)(st + 1), __ATOMIC_RELAXED,
                         __HIP_MEMORY_SCOPE_AGENT);

    if (t + 1 < kT) {
      #pragma unroll
      for (int i = 0; i < 4; ++i) { zc0[i] = zn0[i]; zc1[i] = zn1[i]; }
    }
  }

  cbuf[cidx] = c0r;
  cbuf[cidx + 512] = c1r;
}

// ---------------------------------------------------------------- gemm_out
__global__ __launch_bounds__(256) void gemm_out_kernel(
    const unsigned short* __restrict__ Hs,   // hsx + 32768: h_1.. in chunked layout
    const unsigned short* __restrict__ WoT,  // [512][512] bf16 (B^T)
    const float* __restrict__ bout,
    float* __restrict__ out)                 // [32768][512] fp32
{
  __shared__ unsigned short Ash[128][40];
  __shared__ unsigned short Bsh[128][40];
  const int row0 = blockIdx.x * 128, col0 = blockIdx.y * 128;
  const int tid = threadIdx.x;
  const int lane = tid & 63, wave = tid >> 6;
  const int wr = wave >> 1, wc = wave & 1;
  const int m16 = lane & 15, kg = (lane >> 4) * 8;

  f32x4 acc[4][4] = {};

  for (int k0 = 0; k0 < 512; k0 += 32) {
    __syncthreads();
    #pragma unroll
    for (int i = 0; i < 2; ++i) {
      int idx = i * 256 + tid;
      int r = idx >> 2, kq = idx & 3;
      int grow = row0 + r;               // h row: t*64 + n  (t = step-1)
      size_t src = (size_t)(grow >> 6) * kHS + (size_t)((k0 >> 3) + kq) * 512 +
                   ((grow >> 4) & 3) * 128 + (grow & 15) * 8;
      *(uint4*)&Ash[r][kq * 8] = *(const uint4*)&Hs[src];
    }
    #pragma unroll
    for (int i = 0; i < 2; ++i) {
      int idx = i * 256 + tid;
      int c = idx >> 2, kq = idx & 3;
      *(uint4*)&Bsh[c][kq * 8] =
          *(const uint4*)&WoT[(size_t)(col0 + c) * 512 + k0 + kq * 8];
    }
    __syncthreads();
    bf16x8 fa[4], fb[4];
    #pragma unroll
    for (int mi = 0; mi < 4; ++mi) fa[mi] = *(const bf16x8*)&Ash[wr*64 + mi*16 + m16][kg];
    #pragma unroll
    for (int ni = 0; ni < 4; ++ni) fb[ni] = *(const bf16x8*)&Bsh[wc*64 + ni*16 + m16][kg];
    #pragma unroll
    for (int mi = 0; mi < 4; ++mi)
      #pragma unroll
      for (int ni = 0; ni < 4; ++ni)
        acc[mi][ni] = __builtin_amdgcn_mfma_f32_16x16x32_bf16(fa[mi], fb[ni], acc[mi][ni], 0, 0, 0);
  }
  const int rg = (lane >> 4) * 4;
  #pragma unroll
  for (int ni = 0; ni < 4; ++ni) {
    int col = col0 + wc*64 + ni*16 + m16;
    float bb = bout[col];
    #pragma unroll
    for (int mi = 0; mi < 4; ++mi)
      #pragma unroll
      for (int r = 0; r < 4; ++r)
        out[(size_t)(row0 + wr*64 + mi*16 + rg + r) * 512 + col] = acc[mi][ni][r] + bb;
  }
}

// ---------------------------------------------------------------- launch
extern "C" void kernel_launch(void* const* d_in, const int* in_sizes, int n_in,
                              void* d_out, int out_size, void* d_ws, size_t ws_size,
                              hipStream_t stream) {
  (void)in_sizes; (void)n_in; (void)out_size; (void)ws_size;
  const float* x    = (const float*)d_in[0];
  const float* h0   = (const float*)d_in[1];
  const float* c0   = (const float*)d_in[2];
  const float* Wf   = (const float*)d_in[3];
  const float* bf_  = (const float*)d_in[4];
  const float* Wc   = (const float*)d_in[5];
  const float* bc_  = (const float*)d_in[6];
  const float* Wi_  = (const float*)d_in[7];
  const float* bi_  = (const float*)d_in[8];
  const float* Wo   = (const float*)d_in[9];
  const float* bo_  = (const float*)d_in[10];
  const float* Wout = (const float*)d_in[11];
  const float* bout = (const float*)d_in[12];
  float* out = (float*)d_out;

  char* ws = (char*)d_ws;
  size_t off = 0;
  auto alloc = [&](size_t bytes) -> void* {
    void* p = ws + off;
    off += (bytes + 255) & ~(size_t)255;
    return p;
  };
  float*          ZxA = (float*)alloc((size_t)kT * kN * kG * 4);                 // 16 MB
  float*          ZxB = (float*)alloc((size_t)kT * kN * kG * 4);                 // 16 MB
  unsigned short* hsx = (unsigned short*)alloc((size_t)(kL + 1) * kN * kDH * 2); // 33.6 MB
  unsigned short* WxT = (unsigned short*)alloc((size_t)kG * 512 * 2);            // 2 MB
  unsigned short* WoT = (unsigned short*)alloc((size_t)512 * 512 * 2);           // 0.5 MB
  unsigned short* WhB = (unsigned short*)alloc((size_t)64 * 32 * 512 * 2);       // 2 MB
  float*          bg  = (float*)alloc((size_t)kG * 4);
  float*          cbf = (float*)alloc((size_t)kN * kDH * 4);
  unsigned int*   flg = (unsigned int*)alloc((size_t)64 * kFP * 4);              // 4 KB

  prep_kernel<<<1024, 256, 0, stream>>>(Wf, Wc, Wi_, Wo, bf_, bc_, bi_, bo_,
                                        Wout, h0, c0, WxT, WoT, WhB, bg, hsx, cbf, flg);
  // chunk 0's Zx
  gemm_x_kernel<<<dim3(16, 16), 256, 0, stream>>>(x, WxT, bg, ZxA);
  for (int c = 0; c < kChunks; ++c) {
    float* Zxcur = (c & 1) ? ZxB : ZxA;
    float* Zxnxt = (c & 1) ? ZxA : ZxB;
    const float* xnext = (c + 1 < kChunks)
        ? x + (size_t)(c + 1) * kT * kN * kDIN : nullptr;
    lstm_fused_kernel<<<256, 256, 0, stream>>>(
        WhB, Zxcur, hsx, cbf, c * kT, flg, out, xnext, WxT, bg, Zxnxt);
  }
  gemm_out_kernel<<<dim3(256, 4), 256, 0, stream>>>(
      hsx + (size_t)kN * kDH, WoT, bout, out);
}